// Round 1
// baseline (876.811 us; speedup 1.0000x reference)
//
#include <hip/hip_runtime.h>
#include <hip/hip_bf16.h>

#define BB 64
#define TT 512
#define EE 768
#define CC 20

// ---------------- emissions: em[b*T+t][c] = dot(hidden[b,t,:], fc_w[c,:]) + fc_b[c]
__global__ __launch_bounds__(256) void emissions_kernel(
    const float* __restrict__ hidden, const float* __restrict__ fc_w,
    const float* __restrict__ fc_b, float* __restrict__ em) {
  int idx = blockIdx.x * 256 + threadIdx.x;        // 0 .. B*T*C-1 (grid sized exactly)
  int token = idx / CC;
  int c = idx - token * CC;
  const float4* hv = (const float4*)(hidden + (size_t)token * EE);
  const float4* wv = (const float4*)(fc_w + (size_t)c * EE);
  float acc = 0.f;
#pragma unroll 4
  for (int k = 0; k < EE / 4; ++k) {
    float4 a = hv[k];
    float4 b = wv[k];
    acc += a.x * b.x + a.y * b.y + a.z * b.z + a.w * b.w;
  }
  em[idx] = acc + fc_b[c];
}

__device__ __forceinline__ void merge_max(float& va, int& ia, float vb, int ib) {
  // first-index tie-break (matches jnp.argmax)
  bool c = (va > vb) || ((va == vb) && (ia < ib));
  va = c ? va : vb;
  ia = c ? ia : ib;
}

__device__ __forceinline__ void argmax20(float* v, int* id) {
#pragma unroll
  for (int q = 0; q < 10; ++q) merge_max(v[q], id[q], v[q + 10], id[q + 10]);
#pragma unroll
  for (int q = 0; q < 5; ++q) merge_max(v[q], id[q], v[q + 5], id[q + 5]);
  merge_max(v[0], id[0], v[1], id[1]);
  merge_max(v[2], id[2], v[3], id[3]);
  merge_max(v[0], id[0], v[2], id[2]);
  merge_max(v[0], id[0], v[4], id[4]);
  // v[0] = max value, id[0] = argmax
}

// ---------------- CRF: blocks 0..63 = forward+numerator (per batch), 64..127 = viterbi
__global__ __launch_bounds__(64) void crf_kernel(
    const float* __restrict__ em, const int* __restrict__ mask,
    const int* __restrict__ labels, const float* __restrict__ st,
    const float* __restrict__ en, const float* __restrict__ tr,
    float* __restrict__ llh, float* __restrict__ out) {
  __shared__ float emsh[TT * CC];
  __shared__ int msh[TT];
  __shared__ unsigned char hist[(TT - 1) * CC];
  const int tid = threadIdx.x;
  const bool is_vit = blockIdx.x >= BB;
  const int b = blockIdx.x & (BB - 1);
  const int cc = tid < CC ? tid : CC - 1;
  const float K = 1.44269504088896340736f;   // 1/ln2
  const float LN2 = 0.69314718055994530942f;

  // stage this batch's emissions + mask into LDS
  {
    const float4* src = (const float4*)(em + (size_t)b * TT * CC);
    float4* dst = (float4*)emsh;
    for (int i = tid; i < TT * CC / 4; i += 64) dst[i] = src[i];
    for (int i = tid; i < TT; i += 64) msh[i] = mask[b * TT + i];
  }
  __syncthreads();

  if (!is_vit) {
    // ======== forward algorithm (denominator), exp-factored:
    // exp(a[q]+tr[q][c]) = E[q] * ET[q][c], alpha kept relative to lane 0.
    float ET[CC];
#pragma unroll
    for (int q = 0; q < CC; ++q) ET[q] = exp2f(tr[q * CC + cc] * K);

    float r = st[cc] + emsh[cc];         // t=0 absolute alpha
    float r0 = __shfl(r, 0);
    float Eself = exp2f((r - r0) * K);   // exp2(alpha_rel * K)
    double off = (double)r0;             // accumulated absolute offset

    float emc = emsh[CC + cc];
    int m = msh[1];
    for (int t = 1; t < TT; ++t) {
      float emc_n = (t + 1 < TT) ? emsh[(t + 1) * CC + cc] : 0.f;  // prefetch
      int m_n = (t + 1 < TT) ? msh[t + 1] : 0;
      if (m != 0) {
        float Eq[CC];
#pragma unroll
        for (int q = 0; q < CC; ++q) Eq[q] = __shfl(Eself, q);
        float s0 = Eq[0] * ET[0], s1 = Eq[1] * ET[1];
        float s2 = Eq[2] * ET[2], s3 = Eq[3] * ET[3];
#pragma unroll
        for (int q = 4; q < CC; q += 4) {
          s0 = fmaf(Eq[q], ET[q], s0);
          s1 = fmaf(Eq[q + 1], ET[q + 1], s1);
          s2 = fmaf(Eq[q + 2], ET[q + 2], s2);
          s3 = fmaf(Eq[q + 3], ET[q + 3], s3);
        }
        float s = (s0 + s1) + (s2 + s3);
        r = fmaf(log2f(s), LN2, emc);    // relative gain for state cc
        r0 = __shfl(r, 0);
        Eself = exp2f((r - r0) * K);
        off += (double)r0;
      }
      emc = emc_n;
      m = m_n;
    }
    // norm = off + lse(alpha_rel + end)
    float Eq[CC];
#pragma unroll
    for (int q = 0; q < CC; ++q) Eq[q] = __shfl(Eself, q);
    float s0 = 0.f, s1 = 0.f, s2 = 0.f, s3 = 0.f;
#pragma unroll
    for (int q = 0; q < CC; q += 4) {
      s0 = fmaf(Eq[q], exp2f(en[q] * K), s0);
      s1 = fmaf(Eq[q + 1], exp2f(en[q + 1] * K), s1);
      s2 = fmaf(Eq[q + 2], exp2f(en[q + 2] * K), s2);
      s3 = fmaf(Eq[q + 3], exp2f(en[q + 3] * K), s3);
    }
    float s = (s0 + s1) + (s2 + s3);
    double norm = off + (double)(log2f(s) * LN2);

    // ======== numerator: gold-path score, lanes parallel over t
    const int* lab = labels + b * TT;
    float sc = 0.f;
    int msum = 0;
    for (int k = tid; k < TT; k += 64) {
      int mk = msh[k];
      msum += mk;
      if (k >= 1) {
        int tg = lab[k], tp = lab[k - 1];
        sc += (tr[tp * CC + tg] + emsh[k * CC + tg]) * (float)mk;
      }
    }
#pragma unroll
    for (int o = 32; o >= 1; o >>= 1) {
      sc += __shfl_xor(sc, o);
      msum += __shfl_xor(msum, o);
    }
    int seq_end = msum - 1;
    int t0 = lab[0], tl = lab[seq_end];
    float score = sc + st[t0] + emsh[t0] + en[tl];
    if (tid == 0) llh[b] = score - (float)norm;
  } else {
    // ======== viterbi forward ========
    float tv[CC];
#pragma unroll
    for (int q = 0; q < CC; ++q) tv[q] = tr[q * CC + cc];
    float a = st[cc] + emsh[cc];
    {
      float r0 = __shfl(a, 0);
      a -= r0;  // keep alpha relative: tiny rounding, shift-invariant argmax
    }
    for (int t = 1; t < TT; ++t) {
      float emc = emsh[t * CC + cc];
      int m = msh[t];
      float aq[CC];
#pragma unroll
      for (int q = 0; q < CC; ++q) aq[q] = __shfl(a, q);
      float v[CC];
      int id[CC];
#pragma unroll
      for (int q = 0; q < CC; ++q) {
        v[q] = aq[q] + tv[q];
        id[q] = q;
      }
      argmax20(v, id);
      if (tid < CC) hist[(t - 1) * CC + tid] = (unsigned char)id[0];
      if (m != 0) {
        float r = v[0] + emc;
        float r0 = __shfl(r, 0);
        a = r - r0;
      }
    }
    // last = argmax(alpha + end) over the 20 real states
    float x = a + en[cc];
    float xq[CC];
    int xi[CC];
#pragma unroll
    for (int q = 0; q < CC; ++q) {
      xq[q] = __shfl(x, q);
      xi[q] = q;
    }
    argmax20(xq, xi);
    int last = xi[0];

    __syncthreads();  // make hist writes safely visible before backtrace reads

    float* ob = out + 1 + (size_t)b * TT;
    if (tid == 0) ob[TT - 1] = (float)(last + 1);
    // ======== backtrace via readlane chain, 8-deep LDS prefetch ========
    int gs[8];
#pragma unroll
    for (int j = 0; j < 8; ++j) gs[j] = (int)hist[(TT - 2 - j) * CC + cc];
    int tag = last;
#pragma unroll 8
    for (int t = TT - 2; t >= 0; --t) {
      int slot = (TT - 2 - t) & 7;
      int g = gs[slot];
      int tp = t - 8;
      gs[slot] = (tp >= 0) ? (int)hist[tp * CC + cc] : 0;
      tag = __builtin_amdgcn_readlane(g, tag);
      if (tid == 0) ob[t] = (float)(tag + 1);
    }
  }
}

__global__ __launch_bounds__(64) void loss_kernel(const float* __restrict__ llh,
                                                  float* __restrict__ out) {
  float v = llh[threadIdx.x];
#pragma unroll
  for (int o = 32; o >= 1; o >>= 1) v += __shfl_xor(v, o);
  if (threadIdx.x == 0) out[0] = -(v * (1.0f / 64.0f));
}

extern "C" void kernel_launch(void* const* d_in, const int* in_sizes, int n_in,
                              void* d_out, int out_size, void* d_ws, size_t ws_size,
                              hipStream_t stream) {
  const float* hidden = (const float*)d_in[0];
  const int* amask = (const int*)d_in[1];
  const int* labels = (const int*)d_in[2];
  const float* fc_w = (const float*)d_in[3];
  const float* fc_b = (const float*)d_in[4];
  const float* st = (const float*)d_in[5];
  const float* en = (const float*)d_in[6];
  const float* tr = (const float*)d_in[7];

  float* emws = (float*)d_ws;                       // B*T*C floats = 2.62 MB
  float* llh = emws + (size_t)BB * TT * CC;         // +64 floats
  float* out = (float*)d_out;

  emissions_kernel<<<(BB * TT * CC) / 256, 256, 0, stream>>>(hidden, fc_w, fc_b, emws);
  crf_kernel<<<2 * BB, 64, 0, stream>>>(emws, amask, labels, st, en, tr, llh, out);
  loss_kernel<<<1, 64, 0, stream>>>(llh, out);
}

// Round 2
// 726.555 us; speedup vs baseline: 1.2068x; 1.2068x over previous
//
#include <hip/hip_runtime.h>
#include <hip/hip_bf16.h>

#define BB 64
#define TT 512
#define EE 768
#define CC 20

__device__ __forceinline__ float rlane(float x, int lane) {
  return __int_as_float(__builtin_amdgcn_readlane(__float_as_int(x), lane));
}

// ---------------- emissions: em[b*T+t][c] = dot(hidden[b,t,:], fc_w[c,:]) + fc_b[c]
// One thread per token, 20 accumulators in VGPRs, fc_w staged in LDS and read
// with uniform-address ds_read_b128 (broadcast, conflict-free).
__global__ __launch_bounds__(128) void emissions_kernel(
    const float* __restrict__ hidden, const float* __restrict__ fc_w,
    const float* __restrict__ fc_b, float* __restrict__ em) {
  __shared__ float wsh[CC * EE];  // 61440 B
  {
    const float4* wsrc = (const float4*)fc_w;
    float4* wdst = (float4*)wsh;
    for (int i = threadIdx.x; i < CC * EE / 4; i += 128) wdst[i] = wsrc[i];
  }
  __syncthreads();
  const int token = blockIdx.x * 128 + threadIdx.x;  // grid sized exactly
  const float4* hv = (const float4*)(hidden + (size_t)token * EE);
  float acc[CC];
#pragma unroll
  for (int c = 0; c < CC; ++c) acc[c] = 0.f;
#pragma unroll 2
  for (int k = 0; k < EE / 4; ++k) {
    float4 h = hv[k];
#pragma unroll
    for (int c = 0; c < CC; ++c) {
      float4 w = ((const float4*)(wsh + c * EE))[k];  // uniform addr -> broadcast
      acc[c] = fmaf(h.x, w.x, fmaf(h.y, w.y, fmaf(h.z, w.z, fmaf(h.w, w.w, acc[c]))));
    }
  }
  float* ep = em + (size_t)token * CC;
#pragma unroll
  for (int c = 0; c < CC; ++c) ep[c] = acc[c] + fc_b[c];
}

__device__ __forceinline__ void merge_max(float& va, int& ia, float vb, int ib) {
  // first-index tie-break (matches jnp.argmax)
  bool c = (va > vb) || ((va == vb) && (ia < ib));
  va = c ? va : vb;
  ia = c ? ia : ib;
}

__device__ __forceinline__ void argmax20(float* v, int* id) {
#pragma unroll
  for (int q = 0; q < 10; ++q) merge_max(v[q], id[q], v[q + 10], id[q + 10]);
#pragma unroll
  for (int q = 0; q < 5; ++q) merge_max(v[q], id[q], v[q + 5], id[q + 5]);
  merge_max(v[0], id[0], v[1], id[1]);
  merge_max(v[2], id[2], v[3], id[3]);
  merge_max(v[0], id[0], v[2], id[2]);
  merge_max(v[0], id[0], v[4], id[4]);
}

// ---------------- CRF: blocks 0..63 = forward+numerator (per batch), 64..127 = viterbi
__global__ __launch_bounds__(64) void crf_kernel(
    const float* __restrict__ em, const int* __restrict__ mask,
    const int* __restrict__ labels, const float* __restrict__ st,
    const float* __restrict__ en, const float* __restrict__ tr,
    float* __restrict__ llh, float* __restrict__ out) {
  __shared__ float emsh[TT * CC];
  __shared__ int msh[TT];
  __shared__ unsigned char hist[(TT - 1) * CC];
  const int tid = threadIdx.x;
  const bool is_vit = blockIdx.x >= BB;
  const int b = blockIdx.x & (BB - 1);
  const int cc = tid < CC ? tid : CC - 1;
  const float K = 1.44269504088896340736f;   // 1/ln2
  const float LN2 = 0.69314718055994530942f;

  // stage this batch's emissions + mask into LDS
  {
    const float4* src = (const float4*)(em + (size_t)b * TT * CC);
    float4* dst = (float4*)emsh;
    for (int i = tid; i < TT * CC / 4; i += 64) dst[i] = src[i];
    for (int i = tid; i < TT; i += 64) msh[i] = mask[b * TT + i];
  }
  __syncthreads();

  if (!is_vit) {
    // ======== forward algorithm (denominator), exp-factored:
    // exp(a[q]+tr[q][c]) = E[q] * ET[q][c], alpha kept relative to lane 0.
    // Broadcasts via v_readlane (VALU, no LDS latency on the critical path).
    float ET[CC];
#pragma unroll
    for (int q = 0; q < CC; ++q) ET[q] = __builtin_amdgcn_exp2f(tr[q * CC + cc] * K);

    float r = st[cc] + emsh[cc];         // t=0 absolute alpha
    float r0 = rlane(r, 0);
    float Eself = __builtin_amdgcn_exp2f((r - r0) * K);
    double off = (double)r0;             // accumulated absolute offset

    for (int t = 1; t < TT; ++t) {
      float emc = emsh[t * CC + cc];
      int m = msh[t];                    // wave-uniform
      if (m != 0) {
        float Eq[CC];
#pragma unroll
        for (int q = 0; q < CC; ++q) Eq[q] = rlane(Eself, q);  // SGPR broadcast
        float s0 = Eq[0] * ET[0], s1 = Eq[1] * ET[1];
        float s2 = Eq[2] * ET[2], s3 = Eq[3] * ET[3];
#pragma unroll
        for (int q = 4; q < CC; q += 4) {
          s0 = fmaf(Eq[q], ET[q], s0);
          s1 = fmaf(Eq[q + 1], ET[q + 1], s1);
          s2 = fmaf(Eq[q + 2], ET[q + 2], s2);
          s3 = fmaf(Eq[q + 3], ET[q + 3], s3);
        }
        float s = (s0 + s1) + (s2 + s3);
        r = fmaf(__builtin_amdgcn_logf(s), LN2, emc);  // relative gain for state cc
        r0 = rlane(r, 0);
        Eself = __builtin_amdgcn_exp2f((r - r0) * K);
        off += (double)r0;
      }
    }
    // norm = off + lse(alpha_rel + end)
    float Eq[CC];
#pragma unroll
    for (int q = 0; q < CC; ++q) Eq[q] = rlane(Eself, q);
    float s0 = 0.f, s1 = 0.f, s2 = 0.f, s3 = 0.f;
#pragma unroll
    for (int q = 0; q < CC; q += 4) {
      s0 = fmaf(Eq[q], __builtin_amdgcn_exp2f(en[q] * K), s0);
      s1 = fmaf(Eq[q + 1], __builtin_amdgcn_exp2f(en[q + 1] * K), s1);
      s2 = fmaf(Eq[q + 2], __builtin_amdgcn_exp2f(en[q + 2] * K), s2);
      s3 = fmaf(Eq[q + 3], __builtin_amdgcn_exp2f(en[q + 3] * K), s3);
    }
    float s = (s0 + s1) + (s2 + s3);
    double norm = off + (double)(__builtin_amdgcn_logf(s) * LN2);

    // ======== numerator: gold-path score, lanes parallel over t
    const int* lab = labels + b * TT;
    float sc = 0.f;
    int msum = 0;
    for (int k = tid; k < TT; k += 64) {
      int mk = msh[k];
      msum += mk;
      if (k >= 1) {
        int tg = lab[k], tp = lab[k - 1];
        sc += (tr[tp * CC + tg] + emsh[k * CC + tg]) * (float)mk;
      }
    }
#pragma unroll
    for (int o = 32; o >= 1; o >>= 1) {
      sc += __shfl_xor(sc, o);
      msum += __shfl_xor(msum, o);
    }
    int seq_end = msum - 1;
    int t0 = lab[0], tl = lab[seq_end];
    float score = sc + st[t0] + emsh[t0] + en[tl];
    if (tid == 0) llh[b] = score - (float)norm;
  } else {
    // ======== viterbi forward ========
    float tv[CC];
#pragma unroll
    for (int q = 0; q < CC; ++q) tv[q] = tr[q * CC + cc];
    float a = st[cc] + emsh[cc];
    a -= rlane(a, 0);  // relative alpha: shift-invariant argmax
    for (int t = 1; t < TT; ++t) {
      float emc = emsh[t * CC + cc];
      int m = msh[t];
      float v[CC];
      int id[CC];
#pragma unroll
      for (int q = 0; q < CC; ++q) {
        v[q] = rlane(a, q) + tv[q];      // SGPR broadcast + lane-local add
        id[q] = q;
      }
      argmax20(v, id);
      if (tid < CC) hist[(t - 1) * CC + tid] = (unsigned char)id[0];
      if (m != 0) {
        float r = v[0] + emc;
        a = r - rlane(r, 0);
      }
    }
    // last = argmax(alpha + end) over the 20 real states
    float x = a + en[cc];
    float xq[CC];
    int xi[CC];
#pragma unroll
    for (int q = 0; q < CC; ++q) {
      xq[q] = rlane(x, q);
      xi[q] = q;
    }
    argmax20(xq, xi);
    int last = xi[0];

    __syncthreads();  // make hist writes visible before backtrace reads

    float* ob = out + 1 + (size_t)b * TT;
    if (tid == 0) ob[TT - 1] = (float)(last + 1);
    // ======== backtrace via readlane chain, 8-deep LDS prefetch ========
    int gs[8];
#pragma unroll
    for (int j = 0; j < 8; ++j) gs[j] = (int)hist[(TT - 2 - j) * CC + cc];
    int tag = last;
#pragma unroll 8
    for (int t = TT - 2; t >= 0; --t) {
      int slot = (TT - 2 - t) & 7;
      int g = gs[slot];
      int tp = t - 8;
      gs[slot] = (tp >= 0) ? (int)hist[tp * CC + cc] : 0;
      tag = __builtin_amdgcn_readlane(g, tag);
      if (tid == 0) ob[t] = (float)(tag + 1);
    }
  }
}

__global__ __launch_bounds__(64) void loss_kernel(const float* __restrict__ llh,
                                                  float* __restrict__ out) {
  float v = llh[threadIdx.x];
#pragma unroll
  for (int o = 32; o >= 1; o >>= 1) v += __shfl_xor(v, o);
  if (threadIdx.x == 0) out[0] = -(v * (1.0f / 64.0f));
}

extern "C" void kernel_launch(void* const* d_in, const int* in_sizes, int n_in,
                              void* d_out, int out_size, void* d_ws, size_t ws_size,
                              hipStream_t stream) {
  const float* hidden = (const float*)d_in[0];
  const int* amask = (const int*)d_in[1];
  const int* labels = (const int*)d_in[2];
  const float* fc_w = (const float*)d_in[3];
  const float* fc_b = (const float*)d_in[4];
  const float* st = (const float*)d_in[5];
  const float* en = (const float*)d_in[6];
  const float* tr = (const float*)d_in[7];

  float* emws = (float*)d_ws;                       // B*T*C floats = 2.62 MB
  float* llh = emws + (size_t)BB * TT * CC;         // +64 floats
  float* out = (float*)d_out;

  emissions_kernel<<<(BB * TT) / 128, 128, 0, stream>>>(hidden, fc_w, fc_b, emws);
  crf_kernel<<<2 * BB, 64, 0, stream>>>(emws, amask, labels, st, en, tr, llh, out);
  loss_kernel<<<1, 64, 0, stream>>>(llh, out);
}

// Round 3
// 328.319 us; speedup vs baseline: 2.6706x; 2.2130x over previous
//
#include <hip/hip_runtime.h>
#include <hip/hip_bf16.h>

#define BB 64
#define TT 512
#define EE 768
#define CC 20

typedef __attribute__((ext_vector_type(8))) short bf16x8;
typedef __attribute__((ext_vector_type(4))) float f32x4;

__device__ __forceinline__ float rlane(float x, int l) {
  return __int_as_float(__builtin_amdgcn_readlane(__float_as_int(x), l));
}
__device__ __forceinline__ short f2bf(float x) {
  union { __hip_bfloat16 h; short s; } u;
  u.h = __float2bfloat16(x);
  return u.s;
}
__device__ __forceinline__ bf16x8 pack8(float4 a, float4 b) {
  bf16x8 r;
  r[0] = f2bf(a.x); r[1] = f2bf(a.y); r[2] = f2bf(a.z); r[3] = f2bf(a.w);
  r[4] = f2bf(b.x); r[5] = f2bf(b.y); r[6] = f2bf(b.z); r[7] = f2bf(b.w);
  return r;
}

// ---------------- emissions via bf16 MFMA: one wave per 16 tokens, 2 N-tiles.
// em[tok][c] = sum_k h[tok][k] * w[c][k] + b[c]   (D = A * B^T, B-op rows = w rows)
__global__ __launch_bounds__(64) void emissions_kernel(
    const float* __restrict__ hidden, const float* __restrict__ fc_w,
    const float* __restrict__ fc_b, float* __restrict__ em) {
  const int lane = threadIdx.x;
  const int mrow = lane & 15;
  const int quad = lane >> 4;
  const int token0 = blockIdx.x * 16;
  const float* hrow = hidden + (size_t)(token0 + mrow) * EE + quad * 8;
  const float* w0 = fc_w + (size_t)mrow * EE + quad * 8;
  const int n1 = (16 + mrow < CC) ? (16 + mrow) : (CC - 1);  // clamp; junk cols unused
  const float* w1 = fc_w + (size_t)n1 * EE + quad * 8;
  f32x4 acc0 = {0.f, 0.f, 0.f, 0.f}, acc1 = {0.f, 0.f, 0.f, 0.f};
  for (int kb = 0; kb < EE; kb += 32) {
    float4 ha = *(const float4*)(hrow + kb);
    float4 hb = *(const float4*)(hrow + kb + 4);
    float4 wa = *(const float4*)(w0 + kb);
    float4 wb = *(const float4*)(w0 + kb + 4);
    float4 xa = *(const float4*)(w1 + kb);
    float4 xb = *(const float4*)(w1 + kb + 4);
    bf16x8 A = pack8(ha, hb);
    bf16x8 B0 = pack8(wa, wb);
    bf16x8 B1 = pack8(xa, xb);
    acc0 = __builtin_amdgcn_mfma_f32_16x16x32_bf16(A, B0, acc0, 0, 0, 0);
    acc1 = __builtin_amdgcn_mfma_f32_16x16x32_bf16(A, B1, acc1, 0, 0, 0);
  }
  const int col = lane & 15;
  const float b0v = fc_b[col];
  const float b1v = (16 + col < CC) ? fc_b[16 + col] : 0.f;
#pragma unroll
  for (int r = 0; r < 4; ++r) {
    int tok = token0 + quad * 4 + r;
    em[(size_t)tok * CC + col] = acc0[r] + b0v;
    if (16 + col < CC) em[(size_t)tok * CC + 16 + col] = acc1[r] + b1v;
  }
}

// ---- named-scalar viterbi merges (no arrays/pointers -> nothing can spill)
#define VDECL(Q) float v##Q = rlane(a, Q) + tv[Q]; int j##Q = Q;
#define MRG(A, B) { bool k_ = (v##A >= v##B); v##A = k_ ? v##A : v##B; j##A = k_ ? j##A : j##B; }
#define XDECL(Q) float x##Q = rlane(x, Q); int y##Q = Q;
#define MRX(A, B) { bool k_ = (x##A >= x##B); x##A = k_ ? x##A : x##B; y##A = k_ ? y##A : y##B; }

// ---------------- CRF: blocks 0..63 = forward+numerator, 64..127 = viterbi
__global__ __launch_bounds__(64) void crf_kernel(
    const float* __restrict__ em, const int* __restrict__ mask,
    const int* __restrict__ labels, const float* __restrict__ st,
    const float* __restrict__ en, const float* __restrict__ tr,
    float* __restrict__ llh, float* __restrict__ out) {
  __shared__ float emsh[TT * CC];
  __shared__ int msh[TT];
  __shared__ unsigned char hist[(TT - 1) * CC];
  const int tid = threadIdx.x;
  const bool is_vit = blockIdx.x >= BB;
  const int b = blockIdx.x & (BB - 1);
  const int cc = tid < CC ? tid : CC - 1;
  const float K = 1.44269504088896340736f;   // 1/ln2
  const float LN2 = 0.69314718055994530942f;

  {
    const float4* src = (const float4*)(em + (size_t)b * TT * CC);
    float4* dst = (float4*)emsh;
    for (int i = tid; i < TT * CC / 4; i += 64) dst[i] = src[i];
    for (int i = tid; i < TT; i += 64) msh[i] = mask[b * TT + i];
  }
  __syncthreads();

  if (!is_vit) {
    // ===== forward (denominator): absolute alpha r, periodic re-centering =====
    float ET[CC];
#pragma unroll
    for (int q = 0; q < CC; ++q) ET[q] = __builtin_amdgcn_exp2f(tr[q * CC + cc] * K);

    float r = st[cc] + emsh[cc];
    float Rb = rlane(r, 0);
    float Es = __builtin_amdgcn_exp2f((r - Rb) * K);
    float emc = emsh[CC + cc];
    for (int t = 1; t < TT; ++t) {
      float emcn = (t + 1 < TT) ? emsh[(t + 1) * CC + cc] : 0.f;  // depth-1 prefetch
      int m = msh[t];
      if (m) {
        float Eq[CC];
#pragma unroll
        for (int q = 0; q < CC; ++q) Eq[q] = rlane(Es, q);
        float s0 = Eq[0] * ET[0], s1 = Eq[1] * ET[1];
        float s2 = Eq[2] * ET[2], s3 = Eq[3] * ET[3];
#pragma unroll
        for (int q = 4; q < CC; q += 4) {
          s0 = fmaf(Eq[q], ET[q], s0);
          s1 = fmaf(Eq[q + 1], ET[q + 1], s1);
          s2 = fmaf(Eq[q + 2], ET[q + 2], s2);
          s3 = fmaf(Eq[q + 3], ET[q + 3], s3);
        }
        float s = (s0 + s1) + (s2 + s3);
        r = fmaf(__builtin_amdgcn_logf(s), LN2, Rb + emc);  // logf builtin == log2
      }
      if ((t & 15) == 15) Rb = rlane(r, 0);  // re-center every 16 steps
      Es = __builtin_amdgcn_exp2f((r - Rb) * K);
      emc = emcn;
    }
    float Eq[CC];
#pragma unroll
    for (int q = 0; q < CC; ++q) Eq[q] = rlane(Es, q);
    float s0 = 0.f, s1 = 0.f, s2 = 0.f, s3 = 0.f;
#pragma unroll
    for (int q = 0; q < CC; q += 4) {
      s0 = fmaf(Eq[q], __builtin_amdgcn_exp2f(en[q] * K), s0);
      s1 = fmaf(Eq[q + 1], __builtin_amdgcn_exp2f(en[q + 1] * K), s1);
      s2 = fmaf(Eq[q + 2], __builtin_amdgcn_exp2f(en[q + 2] * K), s2);
      s3 = fmaf(Eq[q + 3], __builtin_amdgcn_exp2f(en[q + 3] * K), s3);
    }
    float s = (s0 + s1) + (s2 + s3);
    float norm = fmaf(__builtin_amdgcn_logf(s), LN2, Rb);

    // ===== numerator: gold-path score, lanes parallel over t =====
    const int* lab = labels + b * TT;
    float sc = 0.f;
    int msum = 0;
    for (int k = tid; k < TT; k += 64) {
      int mk = msh[k];
      msum += mk;
      if (k >= 1) {
        int tg = lab[k], tp = lab[k - 1];
        sc += (tr[tp * CC + tg] + emsh[k * CC + tg]) * (float)mk;
      }
    }
#pragma unroll
    for (int o = 32; o >= 1; o >>= 1) {
      sc += __shfl_xor(sc, o);
      msum += __shfl_xor(msum, o);
    }
    int seq_end = msum - 1;
    int t0 = lab[0], tl = lab[seq_end];
    float score = sc + st[t0] + emsh[t0] + en[tl];
    if (tid == 0) llh[b] = score - norm;
  } else {
    // ===== viterbi forward, named-scalar argmax =====
    float tv[CC];
#pragma unroll
    for (int q = 0; q < CC; ++q) tv[q] = tr[q * CC + cc];
    float a = st[cc] + emsh[cc];           // absolute alpha (max-plus: no overflow)
    float emc = emsh[CC + cc];
    for (int t = 1; t < TT; ++t) {
      float emcn = (t + 1 < TT) ? emsh[(t + 1) * CC + cc] : 0.f;
      int m = msh[t];
      VDECL(0) VDECL(1) VDECL(2) VDECL(3) VDECL(4) VDECL(5) VDECL(6) VDECL(7)
      VDECL(8) VDECL(9) VDECL(10) VDECL(11) VDECL(12) VDECL(13) VDECL(14)
      VDECL(15) VDECL(16) VDECL(17) VDECL(18) VDECL(19)
      MRG(0, 10) MRG(1, 11) MRG(2, 12) MRG(3, 13) MRG(4, 14)
      MRG(5, 15) MRG(6, 16) MRG(7, 17) MRG(8, 18) MRG(9, 19)
      MRG(0, 5) MRG(1, 6) MRG(2, 7) MRG(3, 8) MRG(4, 9)
      MRG(0, 1) MRG(2, 3)
      MRG(0, 2) MRG(0, 4)
      if (tid < CC) hist[(t - 1) * CC + tid] = (unsigned char)j0;
      if (m) a = v0 + emc;
      emc = emcn;
    }
    float x = a + en[cc];
    XDECL(0) XDECL(1) XDECL(2) XDECL(3) XDECL(4) XDECL(5) XDECL(6) XDECL(7)
    XDECL(8) XDECL(9) XDECL(10) XDECL(11) XDECL(12) XDECL(13) XDECL(14)
    XDECL(15) XDECL(16) XDECL(17) XDECL(18) XDECL(19)
    MRX(0, 10) MRX(1, 11) MRX(2, 12) MRX(3, 13) MRX(4, 14)
    MRX(5, 15) MRX(6, 16) MRX(7, 17) MRX(8, 18) MRX(9, 19)
    MRX(0, 5) MRX(1, 6) MRX(2, 7) MRX(3, 8) MRX(4, 9)
    MRX(0, 1) MRX(2, 3)
    MRX(0, 2) MRX(0, 4)
    int last = y0;

    __syncthreads();  // hist visible

    float* ob = out + 1 + (size_t)b * TT;
    if (tid == 0) ob[TT - 1] = (float)(last + 1);
    // backtrace: readlane chain, 8-deep LDS prefetch
    int gs[8];
#pragma unroll
    for (int j = 0; j < 8; ++j) gs[j] = (int)hist[(TT - 2 - j) * CC + cc];
    int tag = last;
#pragma unroll 8
    for (int t = TT - 2; t >= 0; --t) {
      int slot = (TT - 2 - t) & 7;
      int g = gs[slot];
      int tp = t - 8;
      gs[slot] = (tp >= 0) ? (int)hist[tp * CC + cc] : 0;
      tag = __builtin_amdgcn_readlane(g, tag);
      if (tid == 0) ob[t] = (float)(tag + 1);
    }
  }
}

__global__ __launch_bounds__(64) void loss_kernel(const float* __restrict__ llh,
                                                  float* __restrict__ out) {
  float v = llh[threadIdx.x];
#pragma unroll
  for (int o = 32; o >= 1; o >>= 1) v += __shfl_xor(v, o);
  if (threadIdx.x == 0) out[0] = -(v * (1.0f / 64.0f));
}

extern "C" void kernel_launch(void* const* d_in, const int* in_sizes, int n_in,
                              void* d_out, int out_size, void* d_ws, size_t ws_size,
                              hipStream_t stream) {
  const float* hidden = (const float*)d_in[0];
  const int* amask = (const int*)d_in[1];
  const int* labels = (const int*)d_in[2];
  const float* fc_w = (const float*)d_in[3];
  const float* fc_b = (const float*)d_in[4];
  const float* st = (const float*)d_in[5];
  const float* en = (const float*)d_in[6];
  const float* tr = (const float*)d_in[7];

  float* emws = (float*)d_ws;                       // B*T*C floats = 2.62 MB
  float* llh = emws + (size_t)BB * TT * CC;         // +64 floats
  float* out = (float*)d_out;

  emissions_kernel<<<(BB * TT) / 16, 64, 0, stream>>>(hidden, fc_w, fc_b, emws);
  crf_kernel<<<2 * BB, 64, 0, stream>>>(emws, amask, labels, st, en, tr, llh, out);
  loss_kernel<<<1, 64, 0, stream>>>(llh, out);
}

// Round 4
// 317.460 us; speedup vs baseline: 2.7620x; 1.0342x over previous
//
#include <hip/hip_runtime.h>
#include <hip/hip_bf16.h>

#define BB 64
#define TT 512
#define EE 768
#define CC 20
#define PADW 772  // LDS row stride (words) for emissions A-tile

typedef __attribute__((ext_vector_type(8))) short bf16x8;
typedef __attribute__((ext_vector_type(4))) float f32x4;

__device__ __forceinline__ float rlane(float x, int l) {
  return __int_as_float(__builtin_amdgcn_readlane(__float_as_int(x), l));
}
__device__ __forceinline__ short f2bf(float x) {
  union { __hip_bfloat16 h; short s; } u;
  u.h = __float2bfloat16(x);
  return u.s;
}
__device__ __forceinline__ bf16x8 pack8(float4 a, float4 b) {
  bf16x8 r;
  r[0] = f2bf(a.x); r[1] = f2bf(a.y); r[2] = f2bf(a.z); r[3] = f2bf(a.w);
  r[4] = f2bf(b.x); r[5] = f2bf(b.y); r[6] = f2bf(b.z); r[7] = f2bf(b.w);
  return r;
}

// ---------------- pre-pack fc_w into B-fragment layout (bf16), so the GEMM's
// B loads are coalesced 16B/lane: wfrag[tile][kc][lane] = 8 bf16.
__global__ __launch_bounds__(256) void packw_kernel(const float* __restrict__ fc_w,
                                                    short* __restrict__ wfrag) {
  int t = blockIdx.x * 256 + threadIdx.x;  // 0 .. 2*24*64-1 (grid exact)
  int lane = t & 63;
  int kc = (t >> 6) % 24;
  int tile = t / (24 * 64);
  int n = tile * 16 + (lane & 15);
  if (n >= CC) n = CC - 1;                 // clamp; junk cols never stored
  int k0 = kc * 32 + (lane >> 4) * 8;
  const float* src = fc_w + (size_t)n * EE + k0;
  float4 x = *(const float4*)src;
  float4 y = *(const float4*)(src + 4);
  ((bf16x8*)wfrag)[t] = pack8(x, y);
}

// ---------------- emissions: coalesced LDS stage of 16 token rows + MFMA.
__global__ __launch_bounds__(64) void emissions_kernel(
    const float* __restrict__ hidden, const short* __restrict__ wfrag,
    const float* __restrict__ fc_b, float* __restrict__ em) {
  __shared__ float A[16 * PADW];  // 49408 B
  const int lane = threadIdx.x;
  const int token0 = blockIdx.x * 16;
  const float* hbase = hidden + (size_t)token0 * EE;
#pragma unroll 8
  for (int i = 0; i < 48; ++i) {          // 48 * 256 floats = 16*768, coalesced
    int flat = i * 256 + lane * 4;
    int row = flat / 768;
    int col = flat - row * 768;
    float4 v = *(const float4*)(hbase + flat);
    *(float4*)(&A[row * PADW + col]) = v;
  }
  __syncthreads();
  const int m = lane & 15, q = lane >> 4;
  const bf16x8* wp = (const bf16x8*)wfrag;
  f32x4 acc0 = {0.f, 0.f, 0.f, 0.f}, acc1 = {0.f, 0.f, 0.f, 0.f};
#pragma unroll 4
  for (int kb = 0; kb < 24; ++kb) {
    const float* ap = &A[m * PADW + kb * 32 + q * 8];
    float4 a0 = *(const float4*)ap;
    float4 a1 = *(const float4*)(ap + 4);
    bf16x8 Ab = pack8(a0, a1);
    bf16x8 w0 = wp[kb * 64 + lane];
    bf16x8 w1 = wp[(24 + kb) * 64 + lane];
    acc0 = __builtin_amdgcn_mfma_f32_16x16x32_bf16(Ab, w0, acc0, 0, 0, 0);
    acc1 = __builtin_amdgcn_mfma_f32_16x16x32_bf16(Ab, w1, acc1, 0, 0, 0);
  }
  const int col = lane & 15;
  const float b0v = fc_b[col];
  const bool has1 = (16 + col < CC);
  const float b1v = has1 ? fc_b[16 + col] : 0.f;
#pragma unroll
  for (int r = 0; r < 4; ++r) {
    int tok = token0 + q * 4 + r;
    em[(size_t)tok * CC + col] = acc0[r] + b0v;
    if (has1) em[(size_t)tok * CC + 16 + col] = acc1[r] + b1v;
  }
}

// ---- named-scalar helpers (nothing spillable)
#define VDECL(Q) float v##Q = rlane(a, Q) + tv[Q]; int j##Q = Q;
#define MRG(A_, B_) { bool k_ = (v##A_ >= v##B_); v##A_ = k_ ? v##A_ : v##B_; j##A_ = k_ ? j##A_ : j##B_; }
__device__ __forceinline__ void vstep(float a, const float (&tv)[CC], float& vm, int& jm) {
  VDECL(0) VDECL(1) VDECL(2) VDECL(3) VDECL(4) VDECL(5) VDECL(6) VDECL(7)
  VDECL(8) VDECL(9) VDECL(10) VDECL(11) VDECL(12) VDECL(13) VDECL(14)
  VDECL(15) VDECL(16) VDECL(17) VDECL(18) VDECL(19)
  MRG(0, 10) MRG(1, 11) MRG(2, 12) MRG(3, 13) MRG(4, 14)
  MRG(5, 15) MRG(6, 16) MRG(7, 17) MRG(8, 18) MRG(9, 19)
  MRG(0, 5) MRG(1, 6) MRG(2, 7) MRG(3, 8) MRG(4, 9)
  MRG(0, 1) MRG(2, 3)
  MRG(0, 2) MRG(0, 4)
  vm = v0; jm = j0;
}
#define XDECL(Q) float x##Q = rlane(x, Q); int y##Q = Q;
#define MRX(A_, B_) { bool k_ = (x##A_ >= x##B_); x##A_ = k_ ? x##A_ : x##B_; y##A_ = k_ ? y##A_ : y##B_; }
__device__ __forceinline__ int lane_argmax(float x) {
  XDECL(0) XDECL(1) XDECL(2) XDECL(3) XDECL(4) XDECL(5) XDECL(6) XDECL(7)
  XDECL(8) XDECL(9) XDECL(10) XDECL(11) XDECL(12) XDECL(13) XDECL(14)
  XDECL(15) XDECL(16) XDECL(17) XDECL(18) XDECL(19)
  MRX(0, 10) MRX(1, 11) MRX(2, 12) MRX(3, 13) MRX(4, 14)
  MRX(5, 15) MRX(6, 16) MRX(7, 17) MRX(8, 18) MRX(9, 19)
  MRX(0, 5) MRX(1, 6) MRX(2, 7) MRX(3, 8) MRX(4, 9)
  MRX(0, 1) MRX(2, 3)
  MRX(0, 2) MRX(0, 4)
  return y0;
}

__device__ __forceinline__ float fdot(float Es, const float (&ET)[CC]) {
  float s0 = rlane(Es, 0) * ET[0];
  float s1 = rlane(Es, 1) * ET[1];
  float s2 = rlane(Es, 2) * ET[2];
  float s3 = rlane(Es, 3) * ET[3];
  s0 = fmaf(rlane(Es, 4), ET[4], s0);
  s1 = fmaf(rlane(Es, 5), ET[5], s1);
  s2 = fmaf(rlane(Es, 6), ET[6], s2);
  s3 = fmaf(rlane(Es, 7), ET[7], s3);
  s0 = fmaf(rlane(Es, 8), ET[8], s0);
  s1 = fmaf(rlane(Es, 9), ET[9], s1);
  s2 = fmaf(rlane(Es, 10), ET[10], s2);
  s3 = fmaf(rlane(Es, 11), ET[11], s3);
  s0 = fmaf(rlane(Es, 12), ET[12], s0);
  s1 = fmaf(rlane(Es, 13), ET[13], s1);
  s2 = fmaf(rlane(Es, 14), ET[14], s2);
  s3 = fmaf(rlane(Es, 15), ET[15], s3);
  s0 = fmaf(rlane(Es, 16), ET[16], s0);
  s1 = fmaf(rlane(Es, 17), ET[17], s1);
  s2 = fmaf(rlane(Es, 18), ET[18], s2);
  s3 = fmaf(rlane(Es, 19), ET[19], s3);
  return (s0 + s1) + (s2 + s3);
}

// ---------------- CRF: blocks 0..63 = forward+numerator, 64..127 = viterbi
__global__ __launch_bounds__(64) void crf_kernel(
    const float* __restrict__ em, const int* __restrict__ mask,
    const int* __restrict__ labels, const float* __restrict__ st,
    const float* __restrict__ en, const float* __restrict__ tr,
    float* __restrict__ llh, float* __restrict__ out) {
  __shared__ float emsh[TT * CC];
  __shared__ int msh[TT];
  __shared__ unsigned char hist[(TT - 1) * CC];
  const int tid = threadIdx.x;
  const bool is_vit = blockIdx.x >= BB;
  const int b = blockIdx.x & (BB - 1);
  const int cc = tid < CC ? tid : CC - 1;
  const float K = 1.44269504088896340736f;   // 1/ln2
  const float LN2 = 0.69314718055994530942f;

  {
    const float4* src = (const float4*)(em + (size_t)b * TT * CC);
    float4* dst = (float4*)emsh;
    for (int i = tid; i < TT * CC / 4; i += 64) dst[i] = src[i];
    for (int i = tid; i < TT; i += 64) msh[i] = mask[b * TT + i];
  }
  __syncthreads();

  if (!is_vit) {
    // ===== forward: linear-domain recurrence, no transcendental on the chain.
    // Es_c ~ exp2(alpha_c*K - off - ie); per step Es' = (sum_q Es_q*ET[q][c]) * exp2(em_c*K).
    float ET[CC];
#pragma unroll
    for (int q = 0; q < CC; ++q) ET[q] = __builtin_amdgcn_exp2f(tr[q * CC + cc] * K);

    float r = st[cc] + emsh[cc];
    float base = rlane(r, 0);
    float Es = __builtin_amdgcn_exp2f((r - base) * K);
    float off = base * K;   // log2-domain offset (float part)
    int ie = 0;             // log2-domain offset (exact integer part)

    float emc = emsh[CC + cc];
    int mcur = msh[1];
    float eec = __builtin_amdgcn_exp2f(emc * K);
    for (int t = 1; t < TT; ++t) {
      int tn = (t + 1 < TT) ? t + 1 : t;
      float emn = emsh[tn * CC + cc];   // prefetch (off-chain)
      int mn = msh[tn];
      float s = fdot(Es, ET) * eec;
      Es = mcur ? s : Es;
      if ((t & 7) == 0) {               // exact power-of-2 rescale
        float p = rlane(Es, 0);
        int e = ((__float_as_int(p) >> 23) & 255) - 127;
        Es *= __int_as_float((127 - e) << 23);
        ie += e;
      }
      eec = __builtin_amdgcn_exp2f(emn * K);
      emc = emn;
      mcur = mn;
    }
    float EN[CC];
#pragma unroll
    for (int q = 0; q < CC; ++q) EN[q] = __builtin_amdgcn_exp2f(en[q] * K);
    float S = fdot(Es, EN);
    float norm = LN2 * (off + (float)ie + __builtin_amdgcn_logf(S));

    // ===== numerator: gold-path score, lanes parallel over t =====
    const int* lab = labels + b * TT;
    float sc = 0.f;
    int msum = 0;
    for (int k = tid; k < TT; k += 64) {
      int mk = msh[k];
      msum += mk;
      if (k >= 1) {
        int tg = lab[k], tp = lab[k - 1];
        sc += (tr[tp * CC + tg] + emsh[k * CC + tg]) * (float)mk;
      }
    }
#pragma unroll
    for (int o = 32; o >= 1; o >>= 1) {
      sc += __shfl_xor(sc, o);
      msum += __shfl_xor(msum, o);
    }
    int seq_end = msum - 1;
    int t0 = lab[0], tl = lab[seq_end];
    float score = sc + st[t0] + emsh[t0] + en[tl];
    if (tid == 0) llh[b] = score - norm;
  } else {
    // ===== viterbi forward: branchless, prefetched =====
    float tv[CC];
#pragma unroll
    for (int q = 0; q < CC; ++q) tv[q] = tr[q * CC + cc];
    float a = st[cc] + emsh[cc];
    float emc = emsh[CC + cc];
    int mcur = msh[1];
    for (int t = 1; t < TT; ++t) {
      int tn = (t + 1 < TT) ? t + 1 : t;
      float emn = emsh[tn * CC + cc];
      int mn = msh[tn];
      float vm;
      int jm;
      vstep(a, tv, vm, jm);
      hist[(t - 1) * CC + cc] = (unsigned char)jm;  // lanes>=20 dup lane 19's value
      float au = vm + emc;
      a = mcur ? au : a;
      emc = emn;
      mcur = mn;
    }
    int last = lane_argmax(a + en[cc]);

    __syncthreads();  // hist writes visible (same wave; cheap safety)

    float* ob = out + 1 + (size_t)b * TT;
    if (tid == 0) ob[TT - 1] = (float)(last + 1);
    int tag = last;
    int t = TT - 2;  // 510; 511 entries total
    while (t >= 7) {  // named registers: compile-time slots, no scratch
      int g0 = hist[(t - 0) * CC + cc];
      int g1 = hist[(t - 1) * CC + cc];
      int g2 = hist[(t - 2) * CC + cc];
      int g3 = hist[(t - 3) * CC + cc];
      int g4 = hist[(t - 4) * CC + cc];
      int g5 = hist[(t - 5) * CC + cc];
      int g6 = hist[(t - 6) * CC + cc];
      int g7 = hist[(t - 7) * CC + cc];
      tag = __builtin_amdgcn_readlane(g0, tag); float f0 = (float)(tag + 1);
      tag = __builtin_amdgcn_readlane(g1, tag); float f1 = (float)(tag + 1);
      tag = __builtin_amdgcn_readlane(g2, tag); float f2 = (float)(tag + 1);
      tag = __builtin_amdgcn_readlane(g3, tag); float f3 = (float)(tag + 1);
      tag = __builtin_amdgcn_readlane(g4, tag); float f4 = (float)(tag + 1);
      tag = __builtin_amdgcn_readlane(g5, tag); float f5 = (float)(tag + 1);
      tag = __builtin_amdgcn_readlane(g6, tag); float f6 = (float)(tag + 1);
      tag = __builtin_amdgcn_readlane(g7, tag); float f7 = (float)(tag + 1);
      if (tid == 0) {
        ob[t - 0] = f0; ob[t - 1] = f1; ob[t - 2] = f2; ob[t - 3] = f3;
        ob[t - 4] = f4; ob[t - 5] = f5; ob[t - 6] = f6; ob[t - 7] = f7;
      }
      t -= 8;
    }
    while (t >= 0) {
      int g = hist[t * CC + cc];
      tag = __builtin_amdgcn_readlane(g, tag);
      if (tid == 0) ob[t] = (float)(tag + 1);
      --t;
    }
  }
}

__global__ __launch_bounds__(64) void loss_kernel(const float* __restrict__ llh,
                                                  float* __restrict__ out) {
  float v = llh[threadIdx.x];
#pragma unroll
  for (int o = 32; o >= 1; o >>= 1) v += __shfl_xor(v, o);
  if (threadIdx.x == 0) out[0] = -(v * (1.0f / 64.0f));
}

extern "C" void kernel_launch(void* const* d_in, const int* in_sizes, int n_in,
                              void* d_out, int out_size, void* d_ws, size_t ws_size,
                              hipStream_t stream) {
  const float* hidden = (const float*)d_in[0];
  const int* amask = (const int*)d_in[1];
  const int* labels = (const int*)d_in[2];
  const float* fc_w = (const float*)d_in[3];
  const float* fc_b = (const float*)d_in[4];
  const float* st = (const float*)d_in[5];
  const float* en = (const float*)d_in[6];
  const float* tr = (const float*)d_in[7];

  float* emws = (float*)d_ws;                         // B*T*C floats = 2.62 MB
  float* llh = emws + (size_t)BB * TT * CC;           // +64 floats
  short* wfrag = (short*)(llh + 64);                  // 2*24*64*8 bf16 = 49 KB
  float* out = (float*)d_out;

  packw_kernel<<<(2 * 24 * 64) / 256, 256, 0, stream>>>(fc_w, wfrag);
  emissions_kernel<<<(BB * TT) / 16, 64, 0, stream>>>(hidden, wfrag, fc_b, emws);
  crf_kernel<<<2 * BB, 64, 0, stream>>>(emws, amask, labels, st, en, tr, llh, out);
  loss_kernel<<<1, 64, 0, stream>>>(llh, out);
}

// Round 5
// 261.980 us; speedup vs baseline: 3.3469x; 1.2118x over previous
//
#include <hip/hip_runtime.h>
#include <hip/hip_bf16.h>

#define BB 64
#define TT 512
#define EE 768
#define CC 20
#define MID 256

typedef __attribute__((ext_vector_type(8))) short bf16x8;
typedef __attribute__((ext_vector_type(4))) float f32x4;

__device__ __forceinline__ float rlane(float x, int l) {
  return __int_as_float(__builtin_amdgcn_readlane(__float_as_int(x), l));
}
__device__ __forceinline__ short f2bf(float x) {
  union { __hip_bfloat16 h; short s; } u;
  u.h = __float2bfloat16(x);
  return u.s;
}
__device__ __forceinline__ bf16x8 pack8(float4 a, float4 b) {
  bf16x8 r;
  r[0] = f2bf(a.x); r[1] = f2bf(a.y); r[2] = f2bf(a.z); r[3] = f2bf(a.w);
  r[4] = f2bf(b.x); r[5] = f2bf(b.y); r[6] = f2bf(b.z); r[7] = f2bf(b.w);
  return r;
}

// ---------------- pre-pack fc_w into B-fragment layout (bf16)
__global__ __launch_bounds__(256) void packw_kernel(const float* __restrict__ fc_w,
                                                    short* __restrict__ wfrag) {
  int t = blockIdx.x * 256 + threadIdx.x;  // 0 .. 2*24*64-1
  int lane = t & 63;
  int kc = (t >> 6) % 24;
  int tile = t / (24 * 64);
  int n = tile * 16 + (lane & 15);
  if (n >= CC) n = CC - 1;
  int k0 = kc * 32 + (lane >> 4) * 8;
  const float* src = fc_w + (size_t)n * EE + k0;
  float4 x = *(const float4*)src;
  float4 y = *(const float4*)(src + 4);
  ((bf16x8*)wfrag)[t] = pack8(x, y);
}

// ---------------- emissions: 4 waves/block, 64 tokens/block, W in LDS, A direct.
__global__ __launch_bounds__(256) void emissions_kernel(
    const float* __restrict__ hidden, const short* __restrict__ wfrag,
    const float* __restrict__ fc_b, float* __restrict__ em) {
  __shared__ short wsh[2 * 24 * 64 * 8];  // 49152 B
  {
    const int4* src = (const int4*)wfrag;
    int4* dst = (int4*)wsh;
    for (int i = threadIdx.x; i < 3072; i += 256) dst[i] = src[i];
  }
  __syncthreads();
  const int wave = threadIdx.x >> 6;
  const int lane = threadIdx.x & 63;
  const int token0 = blockIdx.x * 64 + wave * 16;
  const int m = lane & 15, q = lane >> 4;
  const float* hrow = hidden + (size_t)(token0 + m) * EE + q * 8;
  const bf16x8* wp = (const bf16x8*)wsh;
  f32x4 acc0 = {0.f, 0.f, 0.f, 0.f}, acc1 = {0.f, 0.f, 0.f, 0.f};
#pragma unroll 4
  for (int kb = 0; kb < 24; ++kb) {
    float4 a0 = *(const float4*)(hrow + kb * 32);
    float4 a1 = *(const float4*)(hrow + kb * 32 + 4);
    bf16x8 Ab = pack8(a0, a1);
    bf16x8 w0 = wp[kb * 64 + lane];
    bf16x8 w1 = wp[(24 + kb) * 64 + lane];
    acc0 = __builtin_amdgcn_mfma_f32_16x16x32_bf16(Ab, w0, acc0, 0, 0, 0);
    acc1 = __builtin_amdgcn_mfma_f32_16x16x32_bf16(Ab, w1, acc1, 0, 0, 0);
  }
  const int col = lane & 15;
  const float b0v = fc_b[col];
  const bool has1 = (16 + col < CC);
  const float b1v = has1 ? fc_b[16 + col] : 0.f;
#pragma unroll
  for (int r = 0; r < 4; ++r) {
    int tok = token0 + q * 4 + r;
    em[(size_t)tok * CC + col] = acc0[r] + b0v;
    if (has1) em[(size_t)tok * CC + 16 + col] = acc1[r] + b1v;
  }
}

// ---- named-scalar helpers
#define VDECL(Q) float v##Q = rlane(a, Q) + tv[Q]; int j##Q = Q;
#define MRG(A_, B_) { bool k_ = (v##A_ >= v##B_); v##A_ = k_ ? v##A_ : v##B_; j##A_ = k_ ? j##A_ : j##B_; }
__device__ __forceinline__ void vstep(float a, const float (&tv)[CC], float& vm, int& jm) {
  VDECL(0) VDECL(1) VDECL(2) VDECL(3) VDECL(4) VDECL(5) VDECL(6) VDECL(7)
  VDECL(8) VDECL(9) VDECL(10) VDECL(11) VDECL(12) VDECL(13) VDECL(14)
  VDECL(15) VDECL(16) VDECL(17) VDECL(18) VDECL(19)
  MRG(0, 10) MRG(1, 11) MRG(2, 12) MRG(3, 13) MRG(4, 14)
  MRG(5, 15) MRG(6, 16) MRG(7, 17) MRG(8, 18) MRG(9, 19)
  MRG(0, 5) MRG(1, 6) MRG(2, 7) MRG(3, 8) MRG(4, 9)
  MRG(0, 1) MRG(2, 3)
  MRG(0, 2) MRG(0, 4)
  vm = v0; jm = j0;
}
#define XDECL(Q) float x##Q = rlane(x, Q); int y##Q = Q;
#define MRX(A_, B_) { bool k_ = (x##A_ >= x##B_); x##A_ = k_ ? x##A_ : x##B_; y##A_ = k_ ? y##A_ : y##B_; }
__device__ __forceinline__ int lane_argmax(float x) {
  XDECL(0) XDECL(1) XDECL(2) XDECL(3) XDECL(4) XDECL(5) XDECL(6) XDECL(7)
  XDECL(8) XDECL(9) XDECL(10) XDECL(11) XDECL(12) XDECL(13) XDECL(14)
  XDECL(15) XDECL(16) XDECL(17) XDECL(18) XDECL(19)
  MRX(0, 10) MRX(1, 11) MRX(2, 12) MRX(3, 13) MRX(4, 14)
  MRX(5, 15) MRX(6, 16) MRX(7, 17) MRX(8, 18) MRX(9, 19)
  MRX(0, 5) MRX(1, 6) MRX(2, 7) MRX(3, 8) MRX(4, 9)
  MRX(0, 1) MRX(2, 3)
  MRX(0, 2) MRX(0, 4)
  return y0;
}

__device__ __forceinline__ float fdot(float Es, const float (&ET)[CC]) {
  float s0 = rlane(Es, 0) * ET[0];
  float s1 = rlane(Es, 1) * ET[1];
  float s2 = rlane(Es, 2) * ET[2];
  float s3 = rlane(Es, 3) * ET[3];
  s0 = fmaf(rlane(Es, 4), ET[4], s0);
  s1 = fmaf(rlane(Es, 5), ET[5], s1);
  s2 = fmaf(rlane(Es, 6), ET[6], s2);
  s3 = fmaf(rlane(Es, 7), ET[7], s3);
  s0 = fmaf(rlane(Es, 8), ET[8], s0);
  s1 = fmaf(rlane(Es, 9), ET[9], s1);
  s2 = fmaf(rlane(Es, 10), ET[10], s2);
  s3 = fmaf(rlane(Es, 11), ET[11], s3);
  s0 = fmaf(rlane(Es, 12), ET[12], s0);
  s1 = fmaf(rlane(Es, 13), ET[13], s1);
  s2 = fmaf(rlane(Es, 14), ET[14], s2);
  s3 = fmaf(rlane(Es, 15), ET[15], s3);
  s0 = fmaf(rlane(Es, 16), ET[16], s0);
  s1 = fmaf(rlane(Es, 17), ET[17], s1);
  s2 = fmaf(rlane(Es, 18), ET[18], s2);
  s3 = fmaf(rlane(Es, 19), ET[19], s3);
  return (s0 + s1) + (s2 + s3);
}

// ---------------- CRF halves. quad: 0=fwd-fore 1=fwd-back 2=vit-fore 3=vit-back
__global__ __launch_bounds__(64) void crf_half_kernel(
    const float* __restrict__ em, const int* __restrict__ mask,
    const float* __restrict__ st, const float* __restrict__ en,
    const float* __restrict__ tr,
    float* __restrict__ amw, float* __restrict__ bmw,
    float* __restrict__ avw, float* __restrict__ bvw,
    unsigned char* __restrict__ bpws, unsigned char* __restrict__ fpws) {
  __shared__ float emsh[(MID + 1) * CC];  // fore: rows 0..256; back: rows 256..511
  __shared__ int msh[TT];
  const int tid = threadIdx.x;
  const int quad = blockIdx.x >> 6;
  const int b = blockIdx.x & (BB - 1);
  const int back = quad & 1;
  const int cc = tid < CC ? tid : CC - 1;
  const float K = 1.44269504088896340736f;

  {
    const float* base = em + (size_t)b * TT * CC + (back ? MID * CC : 0);
    int nf4 = back ? (MID * CC / 4) : ((MID + 1) * CC / 4);  // 1280 or 1285
    const float4* src = (const float4*)base;
    float4* dst = (float4*)emsh;
    for (int i = tid; i < nf4; i += 64) dst[i] = src[i];
    for (int i = tid; i < TT; i += 64) msh[i] = mask[b * TT + i];
  }
  __syncthreads();

  if (quad == 0) {
    // ===== forward alpha, t=0..MID, linear domain =====
    float ET[CC];
#pragma unroll
    for (int q = 0; q < CC; ++q) ET[q] = __builtin_amdgcn_exp2f(tr[q * CC + cc] * K);
    float r = st[cc] + emsh[cc];
    float base0 = rlane(r, 0);
    float Es = __builtin_amdgcn_exp2f((r - base0) * K);
    float off = base0 * K;
    int ie = 0;
    float emc = emsh[CC + cc];
    int mcur = msh[1];
    float eec = __builtin_amdgcn_exp2f(emc * K);
    for (int t = 1; t <= MID; ++t) {
      int tn = (t < MID) ? t + 1 : t;
      float emn = emsh[tn * CC + cc];
      int mn = msh[tn];
      float s = fdot(Es, ET) * eec;
      Es = mcur ? s : Es;
      if ((t & 7) == 0) {
        float p = rlane(Es, 0);
        int e = ((__float_as_int(p) >> 23) & 255) - 127;
        Es *= __int_as_float((127 - e) << 23);
        ie += e;
      }
      eec = __builtin_amdgcn_exp2f(emn * K);
      mcur = mn;
    }
    if (tid < CC) amw[b * CC + tid] = off + (float)ie + __builtin_amdgcn_logf(Es);
  } else if (quad == 1) {
    // ===== backward beta, t=T-2..MID, linear domain, mask-reset to en =====
    float ETr[CC];
#pragma unroll
    for (int q = 0; q < CC; ++q) ETr[q] = __builtin_amdgcn_exp2f(tr[cc * CC + q] * K);
    const float ENc = __builtin_amdgcn_exp2f(en[cc] * K);
    float Bs = ENc;
    int ie = 0;
    float em1 = emsh[(TT - 1 - MID) * CC + cc];  // em_{511}
    int m1 = msh[TT - 1];
    float ee1 = __builtin_amdgcn_exp2f(em1 * K);
    for (int t = TT - 2; t >= MID; --t) {
      float emn = emsh[(t - MID) * CC + cc];  // em_t (next iter's em_{t+1})
      int mn = msh[t];
      float G = Bs * ee1;
      float s = fdot(G, ETr);
      Bs = m1 ? s : ENc;
      ie = m1 ? ie : 0;
      if ((t & 7) == 0) {
        float p = rlane(Bs, 0);
        int e = ((__float_as_int(p) >> 23) & 255) - 127;
        Bs *= __int_as_float((127 - e) << 23);
        ie += e;
      }
      ee1 = __builtin_amdgcn_exp2f(emn * K);
      m1 = mn;
    }
    if (tid < CC) bmw[b * CC + tid] = (float)ie + __builtin_amdgcn_logf(Bs);
  } else if (quad == 2) {
    // ===== viterbi fore, t=1..MID, backpointers to global =====
    float tv[CC];
#pragma unroll
    for (int q = 0; q < CC; ++q) tv[q] = tr[q * CC + cc];
    float a = st[cc] + emsh[cc];
    float emc = emsh[CC + cc];
    int mcur = msh[1];
    unsigned char* bp = bpws + (size_t)b * MID * CC;
    for (int t = 1; t <= MID; ++t) {
      int tn = (t < MID) ? t + 1 : t;
      float emn = emsh[tn * CC + cc];
      int mn = msh[tn];
      float vm;
      int jm;
      vstep(a, tv, vm, jm);
      if (tid < CC) bp[(t - 1) * CC + tid] = (unsigned char)jm;
      float au = vm + emc;
      a = mcur ? au : a;
      emc = emn;
      mcur = mn;
    }
    if (tid < CC) avw[b * CC + tid] = a;
  } else {
    // ===== viterbi back, t=T-2..MID, forward-pointers to global =====
    float tv[CC];
#pragma unroll
    for (int q = 0; q < CC; ++q) tv[q] = tr[cc * CC + q];  // row of tr
    const float ENv = en[cc];
    float Vb = ENv;
    float em1 = emsh[(TT - 1 - MID) * CC + cc];
    int m1 = msh[TT - 1];
    unsigned char* fp = fpws + (size_t)b * MID * CC;
    for (int t = TT - 2; t >= MID; --t) {
      float emn = emsh[(t - MID) * CC + cc];
      int mn = msh[t];
      float a = Vb + em1;  // broadcast operand
      float vm;
      int jm;
      vstep(a, tv, vm, jm);
      if (tid < CC) fp[(t - MID) * CC + tid] = (unsigned char)jm;
      Vb = m1 ? vm : ENv;
      em1 = emn;
      m1 = mn;
    }
    if (tid < CC) bvw[b * CC + tid] = Vb;
  }
}

// ---------------- finish: join halves, backtrace both ways, numerator, llh
__global__ __launch_bounds__(64) void finish_kernel(
    const float* __restrict__ em, const int* __restrict__ mask,
    const int* __restrict__ labels, const float* __restrict__ st,
    const float* __restrict__ en, const float* __restrict__ tr,
    const float* __restrict__ amw, const float* __restrict__ bmw,
    const float* __restrict__ avw, const float* __restrict__ bvw,
    const unsigned char* __restrict__ bpws, const unsigned char* __restrict__ fpws,
    float* __restrict__ llh, float* __restrict__ out) {
  __shared__ unsigned char hl[2 * MID * CC];  // 10240
  const int b = blockIdx.x;
  const int tid = threadIdx.x;
  const int cc = tid < CC ? tid : CC - 1;
  const float LN2 = 0.69314718055994530942f;
  {
    const int4* bsrc = (const int4*)(bpws + (size_t)b * MID * CC);
    const int4* fsrc = (const int4*)(fpws + (size_t)b * MID * CC);
    int4* dst = (int4*)hl;
    for (int i = tid; i < 320; i += 64) {
      dst[i] = bsrc[i];
      dst[320 + i] = fsrc[i];
    }
  }
  __syncthreads();

  // --- viterbi join + dual backtrace ---
  int cstar = lane_argmax(avw[b * CC + cc] + bvw[b * CC + cc]);
  float* ob = out + 1 + (size_t)b * TT;
  if (tid == 0) ob[MID] = (float)(cstar + 1);
  // backward: s = 255..0, tag_s = bp[s][tag_{s+1}] ; 256 = 32*8 exact
  {
    int tag = cstar;
    int s = MID - 1;
    while (s >= 7) {
      int g0 = hl[(s - 0) * CC + cc];
      int g1 = hl[(s - 1) * CC + cc];
      int g2 = hl[(s - 2) * CC + cc];
      int g3 = hl[(s - 3) * CC + cc];
      int g4 = hl[(s - 4) * CC + cc];
      int g5 = hl[(s - 5) * CC + cc];
      int g6 = hl[(s - 6) * CC + cc];
      int g7 = hl[(s - 7) * CC + cc];
      tag = __builtin_amdgcn_readlane(g0, tag); float f0 = (float)(tag + 1);
      tag = __builtin_amdgcn_readlane(g1, tag); float f1 = (float)(tag + 1);
      tag = __builtin_amdgcn_readlane(g2, tag); float f2 = (float)(tag + 1);
      tag = __builtin_amdgcn_readlane(g3, tag); float f3 = (float)(tag + 1);
      tag = __builtin_amdgcn_readlane(g4, tag); float f4 = (float)(tag + 1);
      tag = __builtin_amdgcn_readlane(g5, tag); float f5 = (float)(tag + 1);
      tag = __builtin_amdgcn_readlane(g6, tag); float f6 = (float)(tag + 1);
      tag = __builtin_amdgcn_readlane(g7, tag); float f7 = (float)(tag + 1);
      if (tid == 0) {
        ob[s - 0] = f0; ob[s - 1] = f1; ob[s - 2] = f2; ob[s - 3] = f3;
        ob[s - 4] = f4; ob[s - 5] = f5; ob[s - 6] = f6; ob[s - 7] = f7;
      }
      s -= 8;
    }
  }
  // forward: u = 0..254, tag_{t+1} = fp[u][tag_t], t = MID+u
  {
    int tag = cstar;
    int u = 0;
    while (u + 7 <= MID - 2) {
      int g0 = hl[MID * CC + (u + 0) * CC + cc];
      int g1 = hl[MID * CC + (u + 1) * CC + cc];
      int g2 = hl[MID * CC + (u + 2) * CC + cc];
      int g3 = hl[MID * CC + (u + 3) * CC + cc];
      int g4 = hl[MID * CC + (u + 4) * CC + cc];
      int g5 = hl[MID * CC + (u + 5) * CC + cc];
      int g6 = hl[MID * CC + (u + 6) * CC + cc];
      int g7 = hl[MID * CC + (u + 7) * CC + cc];
      tag = __builtin_amdgcn_readlane(g0, tag); float f0 = (float)(tag + 1);
      tag = __builtin_amdgcn_readlane(g1, tag); float f1 = (float)(tag + 1);
      tag = __builtin_amdgcn_readlane(g2, tag); float f2 = (float)(tag + 1);
      tag = __builtin_amdgcn_readlane(g3, tag); float f3 = (float)(tag + 1);
      tag = __builtin_amdgcn_readlane(g4, tag); float f4 = (float)(tag + 1);
      tag = __builtin_amdgcn_readlane(g5, tag); float f5 = (float)(tag + 1);
      tag = __builtin_amdgcn_readlane(g6, tag); float f6 = (float)(tag + 1);
      tag = __builtin_amdgcn_readlane(g7, tag); float f7 = (float)(tag + 1);
      if (tid == 0) {
        ob[MID + 1 + u + 0] = f0; ob[MID + 1 + u + 1] = f1;
        ob[MID + 1 + u + 2] = f2; ob[MID + 1 + u + 3] = f3;
        ob[MID + 1 + u + 4] = f4; ob[MID + 1 + u + 5] = f5;
        ob[MID + 1 + u + 6] = f6; ob[MID + 1 + u + 7] = f7;
      }
      u += 8;
    }
    while (u <= MID - 2) {
      int g = hl[MID * CC + u * CC + cc];
      tag = __builtin_amdgcn_readlane(g, tag);
      if (tid == 0) ob[MID + 1 + u] = (float)(tag + 1);
      ++u;
    }
  }

  // --- norm = LN2 * lse2(am + bm) ---
  float zn = amw[b * CC + cc] + bmw[b * CC + cc];
  float M = zn;
#pragma unroll
  for (int o = 32; o >= 1; o >>= 1) M = fmaxf(M, __shfl_xor(M, o));
  float sE = (tid < CC) ? __builtin_amdgcn_exp2f(zn - M) : 0.f;
#pragma unroll
  for (int o = 32; o >= 1; o >>= 1) sE += __shfl_xor(sE, o);
  float norm = LN2 * (M + __builtin_amdgcn_logf(sE));

  // --- numerator ---
  const int* lab = labels + b * TT;
  const float* emg = em + (size_t)b * TT * CC;
  float sc = 0.f;
  int msum = 0;
  for (int k = tid; k < TT; k += 64) {
    int mk = mask[b * TT + k];
    msum += mk;
    if (k >= 1) {
      int tg = lab[k], tp = lab[k - 1];
      sc += (tr[tp * CC + tg] + emg[k * CC + tg]) * (float)mk;
    }
  }
#pragma unroll
  for (int o = 32; o >= 1; o >>= 1) {
    sc += __shfl_xor(sc, o);
    msum += __shfl_xor(msum, o);
  }
  int seq_end = msum - 1;
  int t0 = lab[0], tl = lab[seq_end];
  float score = sc + st[t0] + emg[t0] + en[tl];
  if (tid == 0) llh[b] = score - norm;
}

__global__ __launch_bounds__(64) void loss_kernel(const float* __restrict__ llh,
                                                  float* __restrict__ out) {
  float v = llh[threadIdx.x];
#pragma unroll
  for (int o = 32; o >= 1; o >>= 1) v += __shfl_xor(v, o);
  if (threadIdx.x == 0) out[0] = -(v * (1.0f / 64.0f));
}

extern "C" void kernel_launch(void* const* d_in, const int* in_sizes, int n_in,
                              void* d_out, int out_size, void* d_ws, size_t ws_size,
                              hipStream_t stream) {
  const float* hidden = (const float*)d_in[0];
  const int* amask = (const int*)d_in[1];
  const int* labels = (const int*)d_in[2];
  const float* fc_w = (const float*)d_in[3];
  const float* fc_b = (const float*)d_in[4];
  const float* st = (const float*)d_in[5];
  const float* en = (const float*)d_in[6];
  const float* tr = (const float*)d_in[7];

  float* emws = (float*)d_ws;                          // 655360 floats
  float* llh = emws + (size_t)BB * TT * CC;            // 64
  short* wfrag = (short*)(llh + 64);                   // 24576 shorts
  float* amw = (float*)(wfrag + 24576);                // 1280
  float* bmw = amw + BB * CC;
  float* avw = bmw + BB * CC;
  float* bvw = avw + BB * CC;
  unsigned char* bpws = (unsigned char*)(bvw + BB * CC);  // 327680 B (16B aligned)
  unsigned char* fpws = bpws + (size_t)BB * MID * CC;     // 327680 B
  float* out = (float*)d_out;

  packw_kernel<<<(2 * 24 * 64) / 256, 256, 0, stream>>>(fc_w, wfrag);
  emissions_kernel<<<(BB * TT) / 64, 256, 0, stream>>>(hidden, wfrag, fc_b, emws);
  crf_half_kernel<<<4 * BB, 64, 0, stream>>>(emws, amask, st, en, tr,
                                             amw, bmw, avw, bvw, bpws, fpws);
  finish_kernel<<<BB, 64, 0, stream>>>(emws, amask, labels, st, en, tr,
                                       amw, bmw, avw, bvw, bpws, fpws, llh, out);
  loss_kernel<<<1, 64, 0, stream>>>(llh, out);
}